// Round 6
// baseline (123.200 us; speedup 1.0000x reference)
//
#include <hip/hip_runtime.h>

// GenomeNet: B=4096, N_IN=W=N_OUT=1024, L=8 hidden, D=16 fan-in.
// R12: clean R7 main kernel (TB=16, lane-pair-split 32B rows, fmaf inner
// loop, 44 VGPR, no spill — R8..R11 experiments all reverted) + edge-slot
// REBALANCING PREPASS.
//   Standing counter: SQ_LDS_BANK_CONFLICT = 7.46M (~3.2k cyc/CU/layer,
//   35% of the dominant LDS-pipe cost). A lane-pair reading row si covers
//   8-bank double-group D = si mod 4; per ds_read slot the wave's 32 pairs
//   multinomial over 4 groups: E[max] ~11.5 vs ideal 8 (the measured 1.5x).
//   Edge order within a node is free (commutative sum), so a tiny prepass
//   stable-sorts each node's 16 edges by color (src mod 4) and rotates by
//   node mod 16: within a 32-node wave-group every slot then sees ~8 of
//   each color -> near-conflict-free by construction.

#define TB       16
#define W_NODES  1024
#define LAYERS   8
#define ROW_H    16                    // halfs per node row (32 B)
#define BUF_H    (W_NODES * ROW_H)     // 16384 halfs = 32 KB

typedef _Float16 h8 __attribute__((ext_vector_type(8)));

__device__ __forceinline__ float fast_tanh(float x) {
    // tanh(x) = 1 - 2/(e^{2x}+1)
    float a = __builtin_amdgcn_exp2f(x * 2.8853900817779268f);
    return 1.0f - 2.0f * __builtin_amdgcn_rcpf(a + 1.0f);
}

// ---- Prepass: per node, stable counting-sort of the 16 (src,w) edges by
// color c = src & 3, then rotate by (node & 15). One thread per node;
// scratch-indexed locals are fine here (runs once, ~us).
__global__ void reorder_edges(const int*   __restrict__ src_h,
                              const float* __restrict__ w_h,
                              const int*   __restrict__ src_o,
                              const float* __restrict__ w_o,
                              int*   __restrict__ rs_h,
                              float* __restrict__ rw_h,
                              int*   __restrict__ rs_o,
                              float* __restrict__ rw_o)
{
    const int node = blockIdx.x * blockDim.x + threadIdx.x;   // 0..9215
    const int*   sp;
    const float* wp;
    int*   sq;
    float* wq;
    if (node < LAYERS * W_NODES) {
        sp = src_h + node * 16;  wp = w_h + node * 16;
        sq = rs_h  + node * 16;  wq = rw_h + node * 16;
    } else if (node < (LAYERS + 1) * W_NODES) {
        const int n = node - LAYERS * W_NODES;
        sp = src_o + n * 16;     wp = w_o + n * 16;
        sq = rs_o  + n * 16;     wq = rw_o + n * 16;
    } else {
        return;
    }
    // node-in-layer & 15 == node & 15 (layer stride 1024 is a multiple of 16)
    const int rot = node & 15;

    int s[16]; float w[16];
    for (int i = 0; i < 16; ++i) { s[i] = sp[i]; w[i] = wp[i]; }

    int ns[16]; float nw[16];
    int pos = 0;
    for (int c = 0; c < 4; ++c)
        for (int i = 0; i < 16; ++i)
            if ((s[i] & 3) == c) { ns[pos] = s[i]; nw[pos] = w[i]; ++pos; }

    for (int k = 0; k < 16; ++k) {
        const int idx = (k + rot) & 15;
        sq[k] = ns[idx];
        wq[k] = nw[idx];
    }
}

// ---- Main kernel: exact R7 structure.
// Gather 16 half-rows (16 B each) for one node with a software pipeline.
__device__ __forceinline__ void gather16_half(const _Float16* __restrict__ rd,
                                              const int* __restrict__ si,
                                              const float* __restrict__ wi,
                                              const int hfo,
                                              float* __restrict__ acc)
{
#define LDV(i) (*(const h8*)(rd + ((si[i] << 4) + hfo)))
#define FMA8(g, w)                                        \
    do {                                                  \
        const float _w = (w);                             \
        _Pragma("unroll")                                 \
        for (int j = 0; j < 8; ++j)                       \
            acc[j] = fmaf((float)(g)[j], _w, acc[j]);     \
    } while (0)

    h8 g0 = LDV(0);  h8 g1 = LDV(1);  h8 g2 = LDV(2);  h8 g3 = LDV(3);
    h8 g4 = LDV(4);  h8 g5 = LDV(5);  h8 g6 = LDV(6);  h8 g7 = LDV(7);

    FMA8(g0, wi[0]);  FMA8(g1, wi[1]);
    g0 = LDV(8);      g1 = LDV(9);
    FMA8(g2, wi[2]);  FMA8(g3, wi[3]);
    g2 = LDV(10);     g3 = LDV(11);
    FMA8(g4, wi[4]);  FMA8(g5, wi[5]);
    g4 = LDV(12);     g5 = LDV(13);
    FMA8(g6, wi[6]);  FMA8(g7, wi[7]);
    g6 = LDV(14);     g7 = LDV(15);

    FMA8(g0, wi[8]);  FMA8(g1, wi[9]);
    FMA8(g2, wi[10]); FMA8(g3, wi[11]);
    FMA8(g4, wi[12]); FMA8(g5, wi[13]);
    FMA8(g6, wi[14]); FMA8(g7, wi[15]);
#undef LDV
#undef FMA8
}

__global__ __launch_bounds__(1024, 4) void genome_net(
    const float* __restrict__ x,
    const int*   __restrict__ src_hidden,
    const float* __restrict__ w_hidden,
    const int*   __restrict__ src_out,
    const float* __restrict__ w_out,
    float*       __restrict__ out)
{
    extern __shared__ _Float16 lds[];
    _Float16* bufA = lds;              // [1024 nodes][16 batch] fp16, 32 KB
    _Float16* bufB = lds + BUF_H;

    const int t   = threadIdx.x;
    const int pr  = t >> 1;            // pair index 0..511
    const int hf  = t & 1;             // which 16 B half of the row
    const int hfo = hf << 3;           // half offset in halfs
    const int b0  = blockIdx.x * TB;
    const int bb  = b0 + hfo;          // this thread's 8-batch base

    // ---- Stage x: fp32 -> fp16 half-rows, 2 node passes. Coalesced.
    #pragma unroll
    for (int p = 0; p < 2; ++p) {
        const int n = (p << 9) + pr;
        h8 hv;
        #pragma unroll
        for (int j = 0; j < 8; ++j)
            hv[j] = (_Float16)x[(size_t)(bb + j) * W_NODES + n];
        *(h8*)(bufA + n * ROW_H + hfo) = hv;   // 8 lanes/quad-group: clean
    }
    __syncthreads();

    _Float16* rd = bufA;
    _Float16* wr = bufB;

    #pragma unroll 1
    for (int l = 0; l < LAYERS; ++l) {
        #pragma unroll
        for (int p = 0; p < 2; ++p) {
            const int n   = (p << 9) + pr;
            const int row = (l << 10) + n;
            const int4*   sp = (const int4*)(src_hidden) + (row << 2);
            const float4* wp = (const float4*)(w_hidden) + (row << 2);
            int4   s4[4]; float4 w4[4];
            #pragma unroll
            for (int q = 0; q < 4; ++q) { s4[q] = sp[q]; w4[q] = wp[q]; }
            int   si[16]; float wi[16];
            #pragma unroll
            for (int q = 0; q < 4; ++q) {
                si[4*q+0] = s4[q].x; si[4*q+1] = s4[q].y;
                si[4*q+2] = s4[q].z; si[4*q+3] = s4[q].w;
                wi[4*q+0] = w4[q].x; wi[4*q+1] = w4[q].y;
                wi[4*q+2] = w4[q].z; wi[4*q+3] = w4[q].w;
            }

            float acc[8];
            #pragma unroll
            for (int j = 0; j < 8; ++j) acc[j] = 0.0f;

            gather16_half(rd, si, wi, hfo, acc);

            h8 hv;
            #pragma unroll
            for (int j = 0; j < 8; ++j) hv[j] = (_Float16)fast_tanh(acc[j]);
            *(h8*)(wr + n * ROW_H + hfo) = hv;  // 8 lanes/quad-group: clean
        }

        __syncthreads();
        _Float16* tmp = rd; rd = wr; wr = tmp;
    }

    // ---- Output layer: identity activation, fp32 accumulate + stores.
    #pragma unroll
    for (int p = 0; p < 2; ++p) {
        const int n = (p << 9) + pr;
        const int4*   sp = (const int4*)(src_out) + (n << 2);
        const float4* wp = (const float4*)(w_out) + (n << 2);
        int4   s4[4]; float4 w4[4];
        #pragma unroll
        for (int q = 0; q < 4; ++q) { s4[q] = sp[q]; w4[q] = wp[q]; }
        int   si[16]; float wi[16];
        #pragma unroll
        for (int q = 0; q < 4; ++q) {
            si[4*q+0] = s4[q].x; si[4*q+1] = s4[q].y;
            si[4*q+2] = s4[q].z; si[4*q+3] = s4[q].w;
            wi[4*q+0] = w4[q].x; wi[4*q+1] = w4[q].y;
            wi[4*q+2] = w4[q].z; wi[4*q+3] = w4[q].w;
        }

        float acc[8];
        #pragma unroll
        for (int j = 0; j < 8; ++j) acc[j] = 0.0f;

        gather16_half(rd, si, wi, hfo, acc);

        // Coalesced 4 KB stores per j across the block.
        #pragma unroll
        for (int j = 0; j < 8; ++j)
            out[(size_t)(bb + j) * W_NODES + n] = acc[j];
    }
}

extern "C" void kernel_launch(void* const* d_in, const int* in_sizes, int n_in,
                              void* d_out, int out_size, void* d_ws, size_t ws_size,
                              hipStream_t stream) {
    const float* x  = (const float*)d_in[0];
    const int*   sh = (const int*)  d_in[1];
    const float* wh = (const float*)d_in[2];
    const int*   so = (const int*)  d_in[3];
    const float* wo = (const float*)d_in[4];
    float* out = (float*)d_out;

    // Workspace layout for reordered edge arrays.
    const size_t SZ_H  = (size_t)LAYERS * W_NODES * 16;   // 131072 elems
    const size_t SZ_O  = (size_t)W_NODES * 16;            //  16384 elems
    const size_t NEED  = (SZ_H + SZ_O) * 8;               // int+float each

    const int*   shp = sh;  const float* whp = wh;
    const int*   sop = so;  const float* wop = wo;

    if (d_ws != nullptr && ws_size >= NEED) {
        int*   rs_h = (int*)d_ws;
        float* rw_h = (float*)((char*)d_ws + SZ_H * 4);
        int*   rs_o = (int*)((char*)d_ws + SZ_H * 8);
        float* rw_o = (float*)((char*)d_ws + SZ_H * 8 + SZ_O * 4);

        const int n_nodes = (LAYERS + 1) * W_NODES;       // 9216
        reorder_edges<<<dim3((n_nodes + 255) / 256), dim3(256), 0, stream>>>(
            sh, wh, so, wo, rs_h, rw_h, rs_o, rw_o);

        shp = rs_h; whp = rw_h; sop = rs_o; wop = rw_o;
    }

    const int shmem = 2 * BUF_H * (int)sizeof(_Float16);   // 65536 B
    hipFuncSetAttribute(reinterpret_cast<const void*>(genome_net),
                        hipFuncAttributeMaxDynamicSharedMemorySize, shmem);

    genome_net<<<dim3(4096 / TB), dim3(1024), shmem, stream>>>(
        x, shp, whp, sop, wop, out);
}

// Round 7
// 119.170 us; speedup vs baseline: 1.0338x; 1.0338x over previous
//
#include <hip/hip_runtime.h>

// GenomeNet: B=4096, N_IN=W=N_OUT=1024, L=8 hidden, D=16 fan-in.
// R13: TB=8, 512-thread blocks, TWO independent blocks (barrier domains)
// per CU.
//   R12 post-mortem: slot-color rebalancing moved conflicts only -8%
//   (sub-wave conflict granularity defeats it) and the prepass cost more
//   than it saved -> dropped. Standing model: LDS pipe ~9.1k cyc/CU/layer
//   busy (73% util) + ~3.3k idle at each layer's barrier convergence
//   window (single barrier domain starves the pipe; R10 showed intra-block
//   issue order can't fix it). Fix: grid=512 blocks of 512 threads (TB=8,
//   full 16B row per thread, 2 node-passes/layer, 32KB LDS/block) ->
//   2 blocks/CU, so block B computes through block A's barrier drain.
//   Unlike old R6 (TB=8 @ launch_bounds(1024,8), 32 VGPR), launch_bounds
//   (512,4) keeps the 128-VGPR budget so the 8-deep pipeline survives.
//   Per-CU LDS instr count / traffic / conflict stats identical to R7.

#define TB       8
#define W_NODES  1024
#define LAYERS   8
#define ROW_H    8                     // halfs per node row (16 B)
#define BUF_H    (W_NODES * ROW_H)     // 8192 halfs = 16 KB

typedef _Float16 h8 __attribute__((ext_vector_type(8)));

__device__ __forceinline__ float fast_tanh(float x) {
    // tanh(x) = 1 - 2/(e^{2x}+1)
    float a = __builtin_amdgcn_exp2f(x * 2.8853900817779268f);
    return 1.0f - 2.0f * __builtin_amdgcn_rcpf(a + 1.0f);
}

// Gather 16 full rows (16 B each) for one node with a software pipeline.
__device__ __forceinline__ void gather16(const _Float16* __restrict__ rd,
                                         const int* __restrict__ si,
                                         const float* __restrict__ wi,
                                         float* __restrict__ acc)
{
#define LDV(i) (*(const h8*)(rd + (si[i] << 3)))
#define FMA8(g, w)                                        \
    do {                                                  \
        const float _w = (w);                             \
        _Pragma("unroll")                                 \
        for (int j = 0; j < 8; ++j)                       \
            acc[j] = fmaf((float)(g)[j], _w, acc[j]);     \
    } while (0)

    h8 g0 = LDV(0);  h8 g1 = LDV(1);  h8 g2 = LDV(2);  h8 g3 = LDV(3);
    h8 g4 = LDV(4);  h8 g5 = LDV(5);  h8 g6 = LDV(6);  h8 g7 = LDV(7);

    FMA8(g0, wi[0]);  FMA8(g1, wi[1]);
    g0 = LDV(8);      g1 = LDV(9);
    FMA8(g2, wi[2]);  FMA8(g3, wi[3]);
    g2 = LDV(10);     g3 = LDV(11);
    FMA8(g4, wi[4]);  FMA8(g5, wi[5]);
    g4 = LDV(12);     g5 = LDV(13);
    FMA8(g6, wi[6]);  FMA8(g7, wi[7]);
    g6 = LDV(14);     g7 = LDV(15);

    FMA8(g0, wi[8]);  FMA8(g1, wi[9]);
    FMA8(g2, wi[10]); FMA8(g3, wi[11]);
    FMA8(g4, wi[12]); FMA8(g5, wi[13]);
    FMA8(g6, wi[14]); FMA8(g7, wi[15]);
#undef LDV
#undef FMA8
}

__global__ __launch_bounds__(512, 4) void genome_net(
    const float* __restrict__ x,
    const int*   __restrict__ src_hidden,
    const float* __restrict__ w_hidden,
    const int*   __restrict__ src_out,
    const float* __restrict__ w_out,
    float*       __restrict__ out)
{
    extern __shared__ _Float16 lds[];
    _Float16* bufA = lds;              // [1024 nodes][8 batch] fp16, 16 KB
    _Float16* bufB = lds + BUF_H;

    const int t  = threadIdx.x;        // 0..511
    const int b0 = blockIdx.x * TB;    // batch tile base

    // ---- Stage x: fp32 -> fp16 rows, 2 node passes.
    // Fixed (p,j): lanes t=0..511 read contiguous 2 KB. Coalesced.
    // Row writes: 64 lanes write 1024 consecutive B -> conflict-free.
    #pragma unroll
    for (int p = 0; p < 2; ++p) {
        const int n = (p << 9) + t;
        h8 hv;
        #pragma unroll
        for (int j = 0; j < TB; ++j)
            hv[j] = (_Float16)x[(size_t)(b0 + j) * W_NODES + n];
        *(h8*)(bufA + n * ROW_H) = hv;
    }
    __syncthreads();

    _Float16* rd = bufA;
    _Float16* wr = bufB;

    #pragma unroll 1
    for (int l = 0; l < LAYERS; ++l) {
        #pragma unroll
        for (int p = 0; p < 2; ++p) {
            const int n   = (p << 9) + t;
            const int row = (l << 10) + n;
            const int4*   sp = (const int4*)(src_hidden) + (row << 2);
            const float4* wp = (const float4*)(w_hidden) + (row << 2);
            int4   s4[4]; float4 w4[4];
            #pragma unroll
            for (int q = 0; q < 4; ++q) { s4[q] = sp[q]; w4[q] = wp[q]; }
            int   si[16]; float wi[16];
            #pragma unroll
            for (int q = 0; q < 4; ++q) {
                si[4*q+0] = s4[q].x; si[4*q+1] = s4[q].y;
                si[4*q+2] = s4[q].z; si[4*q+3] = s4[q].w;
                wi[4*q+0] = w4[q].x; wi[4*q+1] = w4[q].y;
                wi[4*q+2] = w4[q].z; wi[4*q+3] = w4[q].w;
            }

            float acc[TB];
            #pragma unroll
            for (int j = 0; j < TB; ++j) acc[j] = 0.0f;

            gather16(rd, si, wi, acc);

            h8 hv;
            #pragma unroll
            for (int j = 0; j < TB; ++j) hv[j] = (_Float16)fast_tanh(acc[j]);
            *(h8*)(wr + n * ROW_H) = hv;   // consecutive rows: conflict-free
        }

        __syncthreads();
        _Float16* tmp = rd; rd = wr; wr = tmp;
    }

    // ---- Output layer: identity activation, fp32 accumulate + stores.
    #pragma unroll
    for (int p = 0; p < 2; ++p) {
        const int n = (p << 9) + t;
        const int4*   sp = (const int4*)(src_out) + (n << 2);
        const float4* wp = (const float4*)(w_out) + (n << 2);
        int4   s4[4]; float4 w4[4];
        #pragma unroll
        for (int q = 0; q < 4; ++q) { s4[q] = sp[q]; w4[q] = wp[q]; }
        int   si[16]; float wi[16];
        #pragma unroll
        for (int q = 0; q < 4; ++q) {
            si[4*q+0] = s4[q].x; si[4*q+1] = s4[q].y;
            si[4*q+2] = s4[q].z; si[4*q+3] = s4[q].w;
            wi[4*q+0] = w4[q].x; wi[4*q+1] = w4[q].y;
            wi[4*q+2] = w4[q].z; wi[4*q+3] = w4[q].w;
        }

        float acc[TB];
        #pragma unroll
        for (int j = 0; j < TB; ++j) acc[j] = 0.0f;

        gather16(rd, si, wi, acc);

        // Fixed j: lanes t=0..511 store contiguous 2 KB. Coalesced.
        #pragma unroll
        for (int j = 0; j < TB; ++j)
            out[(size_t)(b0 + j) * W_NODES + n] = acc[j];
    }
}

extern "C" void kernel_launch(void* const* d_in, const int* in_sizes, int n_in,
                              void* d_out, int out_size, void* d_ws, size_t ws_size,
                              hipStream_t stream) {
    const float* x  = (const float*)d_in[0];
    const int*   sh = (const int*)  d_in[1];
    const float* wh = (const float*)d_in[2];
    const int*   so = (const int*)  d_in[3];
    const float* wo = (const float*)d_in[4];
    float* out = (float*)d_out;

    const int shmem = 2 * BUF_H * (int)sizeof(_Float16);   // 32768 B
    hipFuncSetAttribute(reinterpret_cast<const void*>(genome_net),
                        hipFuncAttributeMaxDynamicSharedMemorySize, shmem);

    genome_net<<<dim3(4096 / TB), dim3(512), shmem, stream>>>(
        x, sh, wh, so, wo, out);
}

// Round 8
// 111.328 us; speedup vs baseline: 1.1066x; 1.0704x over previous
//
#include <hip/hip_runtime.h>

// GenomeNet: B=4096, N_IN=W=N_OUT=1024, L=8 hidden, D=16 fan-in.
// R14 = R7 REVERT (session-best: 109.8 us bench / ~46-48 us dispatch).
//   Post-R13 standing: seven experiments (VALU: R8,R11; VMEM prefetch: R9;
//   LDS issue order: R10; conflict rebalance: R12; barrier domains: R13)
//   all neutral-or-worse vs this kernel. Model: LDS pipe is the ceiling
//   resource (~9.1k cyc/CU/layer = 512 ds_read_b128 x ~12cyc + ~3k
//   intrinsic random-gather conflicts, ~73% util); residual idle is
//   barrier-locked convoying of in-order-retired LDS reads, not
//   addressable at HIP source level per the evidence. Practical plateau.
//
// Structure: TB=16 batch tile, 256 blocks x 1024 threads.
//  - LDS rows 32 B fp16 ([node][16 batch]); thread pair (2k,2k+1) per
//    node, each thread gathers the 16 B half-row for its 8 batches:
//    addr = 32*si + 16*(t&1). Even lanes -> quad-bank groups {0,8,16,24},
//    odd -> {4,12,20,28}: conflicts 9.57M -> 7.46M vs full-row layout.
//  - Weight/index L2 traffic halved vs TB=8 (128 KB/layer amortized
//    over 16 batches).
//  - launch_bounds(1024,4): 128-VGPR budget keeps the 8-deep ds_read
//    pipeline in flight (compiles to 44 VGPR, zero spill).

#define TB       16
#define W_NODES  1024
#define LAYERS   8
#define ROW_H    16                    // halfs per node row (32 B)
#define BUF_H    (W_NODES * ROW_H)     // 16384 halfs = 32 KB

typedef _Float16 h8 __attribute__((ext_vector_type(8)));

__device__ __forceinline__ float fast_tanh(float x) {
    // tanh(x) = 1 - 2/(e^{2x}+1)
    float a = __builtin_amdgcn_exp2f(x * 2.8853900817779268f);
    return 1.0f - 2.0f * __builtin_amdgcn_rcpf(a + 1.0f);
}

// Gather 16 half-rows (16 B each) for one node with a software pipeline.
// hfo = half-offset in halfs (0 or 8). Accumulates this thread's 8 batches.
__device__ __forceinline__ void gather16_half(const _Float16* __restrict__ rd,
                                              const int* __restrict__ si,
                                              const float* __restrict__ wi,
                                              const int hfo,
                                              float* __restrict__ acc)
{
#define LDV(i) (*(const h8*)(rd + ((si[i] << 4) + hfo)))
#define FMA8(g, w)                                        \
    do {                                                  \
        const float _w = (w);                             \
        _Pragma("unroll")                                 \
        for (int j = 0; j < 8; ++j)                       \
            acc[j] = fmaf((float)(g)[j], _w, acc[j]);     \
    } while (0)

    h8 g0 = LDV(0);  h8 g1 = LDV(1);  h8 g2 = LDV(2);  h8 g3 = LDV(3);
    h8 g4 = LDV(4);  h8 g5 = LDV(5);  h8 g6 = LDV(6);  h8 g7 = LDV(7);

    FMA8(g0, wi[0]);  FMA8(g1, wi[1]);
    g0 = LDV(8);      g1 = LDV(9);
    FMA8(g2, wi[2]);  FMA8(g3, wi[3]);
    g2 = LDV(10);     g3 = LDV(11);
    FMA8(g4, wi[4]);  FMA8(g5, wi[5]);
    g4 = LDV(12);     g5 = LDV(13);
    FMA8(g6, wi[6]);  FMA8(g7, wi[7]);
    g6 = LDV(14);     g7 = LDV(15);

    FMA8(g0, wi[8]);  FMA8(g1, wi[9]);
    FMA8(g2, wi[10]); FMA8(g3, wi[11]);
    FMA8(g4, wi[12]); FMA8(g5, wi[13]);
    FMA8(g6, wi[14]); FMA8(g7, wi[15]);
#undef LDV
#undef FMA8
}

__global__ __launch_bounds__(1024, 4) void genome_net(
    const float* __restrict__ x,
    const int*   __restrict__ src_hidden,
    const float* __restrict__ w_hidden,
    const int*   __restrict__ src_out,
    const float* __restrict__ w_out,
    float*       __restrict__ out)
{
    extern __shared__ _Float16 lds[];
    _Float16* bufA = lds;              // [1024 nodes][16 batch] fp16, 32 KB
    _Float16* bufB = lds + BUF_H;

    const int t   = threadIdx.x;
    const int pr  = t >> 1;            // pair index 0..511
    const int hf  = t & 1;             // which 16 B half of the row
    const int hfo = hf << 3;           // half offset in halfs
    const int b0  = blockIdx.x * TB;
    const int bb  = b0 + hfo;          // this thread's 8-batch base

    // ---- Stage x: fp32 -> fp16 half-rows, 2 node passes. Coalesced.
    #pragma unroll
    for (int p = 0; p < 2; ++p) {
        const int n = (p << 9) + pr;
        h8 hv;
        #pragma unroll
        for (int j = 0; j < 8; ++j)
            hv[j] = (_Float16)x[(size_t)(bb + j) * W_NODES + n];
        *(h8*)(bufA + n * ROW_H + hfo) = hv;   // 8 lanes/quad-group: clean
    }
    __syncthreads();

    _Float16* rd = bufA;
    _Float16* wr = bufB;

    #pragma unroll 1
    for (int l = 0; l < LAYERS; ++l) {
        #pragma unroll
        for (int p = 0; p < 2; ++p) {
            const int n   = (p << 9) + pr;
            const int row = (l << 10) + n;
            const int4*   sp = (const int4*)(src_hidden) + (row << 2);
            const float4* wp = (const float4*)(w_hidden) + (row << 2);
            int4   s4[4]; float4 w4[4];
            #pragma unroll
            for (int q = 0; q < 4; ++q) { s4[q] = sp[q]; w4[q] = wp[q]; }
            int   si[16]; float wi[16];
            #pragma unroll
            for (int q = 0; q < 4; ++q) {
                si[4*q+0] = s4[q].x; si[4*q+1] = s4[q].y;
                si[4*q+2] = s4[q].z; si[4*q+3] = s4[q].w;
                wi[4*q+0] = w4[q].x; wi[4*q+1] = w4[q].y;
                wi[4*q+2] = w4[q].z; wi[4*q+3] = w4[q].w;
            }

            float acc[8];
            #pragma unroll
            for (int j = 0; j < 8; ++j) acc[j] = 0.0f;

            gather16_half(rd, si, wi, hfo, acc);

            h8 hv;
            #pragma unroll
            for (int j = 0; j < 8; ++j) hv[j] = (_Float16)fast_tanh(acc[j]);
            *(h8*)(wr + n * ROW_H + hfo) = hv;  // 8 lanes/quad-group: clean
        }

        __syncthreads();
        _Float16* tmp = rd; rd = wr; wr = tmp;
    }

    // ---- Output layer: identity activation, fp32 accumulate + stores.
    #pragma unroll
    for (int p = 0; p < 2; ++p) {
        const int n = (p << 9) + pr;
        const int4*   sp = (const int4*)(src_out) + (n << 2);
        const float4* wp = (const float4*)(w_out) + (n << 2);
        int4   s4[4]; float4 w4[4];
        #pragma unroll
        for (int q = 0; q < 4; ++q) { s4[q] = sp[q]; w4[q] = wp[q]; }
        int   si[16]; float wi[16];
        #pragma unroll
        for (int q = 0; q < 4; ++q) {
            si[4*q+0] = s4[q].x; si[4*q+1] = s4[q].y;
            si[4*q+2] = s4[q].z; si[4*q+3] = s4[q].w;
            wi[4*q+0] = w4[q].x; wi[4*q+1] = w4[q].y;
            wi[4*q+2] = w4[q].z; wi[4*q+3] = w4[q].w;
        }

        float acc[8];
        #pragma unroll
        for (int j = 0; j < 8; ++j) acc[j] = 0.0f;

        gather16_half(rd, si, wi, hfo, acc);

        // Coalesced: fixed j -> even lanes contiguous 128 B, odd likewise.
        #pragma unroll
        for (int j = 0; j < 8; ++j)
            out[(size_t)(bb + j) * W_NODES + n] = acc[j];
    }
}

extern "C" void kernel_launch(void* const* d_in, const int* in_sizes, int n_in,
                              void* d_out, int out_size, void* d_ws, size_t ws_size,
                              hipStream_t stream) {
    const float* x  = (const float*)d_in[0];
    const int*   sh = (const int*)  d_in[1];
    const float* wh = (const float*)d_in[2];
    const int*   so = (const int*)  d_in[3];
    const float* wo = (const float*)d_in[4];
    float* out = (float*)d_out;

    const int shmem = 2 * BUF_H * (int)sizeof(_Float16);   // 65536 B
    hipFuncSetAttribute(reinterpret_cast<const void*>(genome_net),
                        hipFuncAttributeMaxDynamicSharedMemorySize, shmem);

    genome_net<<<dim3(4096 / TB), dim3(1024), shmem, stream>>>(
        x, sh, wh, so, wo, out);
}